// Round 13
// baseline (1095.290 us; speedup 1.0000x reference)
//
#include <hip/hip_runtime.h>
#include <cstdint>

#define NNODES 40000
#define INDIM 2000
#define HIDD 512
#define ODIM 30
#define NEDGES 400000
#define KPAD 2048
#define ROWSPLIT 20224              // 79 panels of 256

typedef short bf16x8 __attribute__((ext_vector_type(8)));
typedef float f32x4 __attribute__((ext_vector_type(4)));

__device__ __forceinline__ float bf2f(ushort u){ union{unsigned int i; float f;} x; x.i = ((unsigned int)u)<<16; return x.f; }
__device__ __forceinline__ ushort f2bf(float v){ union{float f; unsigned int u;} x; x.f=v; unsigned int r = x.u + 0x7fffu + ((x.u>>16)&1u); return (ushort)(r>>16); }

__device__ __forceinline__ int xcd_swz(int orig, int nwg){
  int q = nwg >> 3, r = nwg & 7;
  int xcd = orig & 7;
  int idx = orig >> 3;
  return (xcd < r ? xcd*(q+1) : r*(q+1) + (xcd-r)*q) + idx;
}

// ---------------- proven 8-phase 256x256 GEMM body (round-6 schedule, unchanged) ----------
#define P_MID  asm volatile("" ::: "memory"); __builtin_amdgcn_s_barrier(); \
               asm volatile("s_waitcnt lgkmcnt(0)" ::: "memory"); \
               __builtin_amdgcn_sched_barrier(0); __builtin_amdgcn_s_setprio(1);
#define P_END  __builtin_amdgcn_s_setprio(0); asm volatile("" ::: "memory"); \
               __builtin_amdgcn_s_barrier(); __builtin_amdgcn_sched_barrier(0);
#define P_ENDW __builtin_amdgcn_s_setprio(0); \
               asm volatile("s_waitcnt vmcnt(4)" ::: "memory"); \
               asm volatile("" ::: "memory"); __builtin_amdgcn_s_barrier(); \
               __builtin_amdgcn_sched_barrier(0);

template<typename OutT>
__device__ __forceinline__ void gemm_body(
    const ushort* __restrict__ A, const ushort* __restrict__ Bt,
    OutT* __restrict__ C, int M, int N, int K, int ldc,
    int row0, int col0, char* smem)
{
  ushort* Al = (ushort*)smem;                // [2][256][64]
  ushort* Bl = (ushort*)(smem + 65536);      // [2][256][64]
  const int tid = threadIdx.x;
  const int lane = tid & 63;
  const int w = tid >> 6;
  const int wm = w >> 2, wn = w & 3;         // 2M x 4N
  const int NT = K >> 6;

  f32x4 acc[8][4] = {};
  bf16x8 a[4][2], b[4][2];

  auto stage = [&](bool isA, int kt, int h){
    const ushort* G = isA ? A : Bt;
    int base = isA ? row0 : col0;
    int lim  = isA ? M : N;
    ushort* L = (isA ? Al : Bl) + ((kt & 1) << 14);
    if (kt >= NT) kt -= NT;
    #pragma unroll
    for (int it = 0; it < 2; ++it){
      int ch = tid + (it << 9);
      int rl = (h << 7) + (ch >> 3);
      int cs = ch & 7;
      int gr = base + rl; gr = gr < lim ? gr : lim - 1;
      int gc = (kt << 6) + ((cs ^ (rl & 7)) << 3);
      __builtin_amdgcn_global_load_lds(
        (const __attribute__((address_space(1))) unsigned int*)(G + (size_t)gr*K + gc),
        (__attribute__((address_space(3))) unsigned int*)(L + rl*64 + cs*8), 16, 0, 0);
    }
  };
  auto lda = [&](int buf, int mf, int kk) -> bf16x8 {
    int rl = wm*128 + mf*16 + (lane & 15);
    int ko = kk*32 + ((lane >> 4) << 3);
    return *(const bf16x8*)&Al[(buf << 14) + rl*64 + (ko ^ ((rl & 7) << 3))];
  };
  auto ldb = [&](int buf, int nf, int kk) -> bf16x8 {
    int rl = wn*64 + nf*16 + (lane & 15);
    int ko = kk*32 + ((lane >> 4) << 3);
    return *(const bf16x8*)&Bl[(buf << 14) + rl*64 + (ko ^ ((rl & 7) << 3))];
  };
  auto mfma_q = [&](int mbase, int nbase){
    #pragma unroll
    for (int i=0;i<4;++i)
      #pragma unroll
      for (int j=0;j<2;++j)
        #pragma unroll
        for (int kk=0;kk<2;++kk)
          acc[mbase+i][nbase+j] = __builtin_amdgcn_mfma_f32_16x16x32_bf16(
              a[i][kk], b[nbase+j][kk], acc[mbase+i][nbase+j], 0, 0, 0);
  };

  stage(false, 0, 0); stage(false, 0, 1);
  stage(true , 0, 0); stage(true , 0, 1);
  stage(false, 1, 0); stage(false, 1, 1);
  asm volatile("s_waitcnt vmcnt(4)" ::: "memory");
  asm volatile("" ::: "memory");
  __builtin_amdgcn_s_barrier();
  __builtin_amdgcn_sched_barrier(0);

  const int NT2 = NT >> 1;
  for (int t = 0; t < NT2; ++t){
    const int kt0 = 2*t, kt1 = 2*t + 1;
    #pragma unroll
    for (int i=0;i<4;++i){ a[i][0]=lda(0,i,0); a[i][1]=lda(0,i,1); }
    #pragma unroll
    for (int j=0;j<2;++j){ b[j][0]=ldb(0,j,0); b[j][1]=ldb(0,j,1); }
    stage(true, kt1, 0);
    P_MID; mfma_q(0,0); P_END;
    #pragma unroll
    for (int j=2;j<4;++j){ b[j][0]=ldb(0,j,0); b[j][1]=ldb(0,j,1); }
    stage(true, kt1, 1);
    P_MID; mfma_q(0,2); P_END;
    #pragma unroll
    for (int i=0;i<4;++i){ a[i][0]=lda(0,4+i,0); a[i][1]=lda(0,4+i,1); }
    stage(false, kt0+2, 0);
    P_MID; mfma_q(4,0); P_END;
    stage(false, kt0+2, 1);
    P_MID; mfma_q(4,2); P_ENDW;
    #pragma unroll
    for (int i=0;i<4;++i){ a[i][0]=lda(1,i,0); a[i][1]=lda(1,i,1); }
    #pragma unroll
    for (int j=0;j<2;++j){ b[j][0]=ldb(1,j,0); b[j][1]=ldb(1,j,1); }
    stage(true, kt0+2, 0);
    P_MID; mfma_q(0,0); P_END;
    #pragma unroll
    for (int j=2;j<4;++j){ b[j][0]=ldb(1,j,0); b[j][1]=ldb(1,j,1); }
    stage(true, kt0+2, 1);
    P_MID; mfma_q(0,2); P_END;
    #pragma unroll
    for (int i=0;i<4;++i){ a[i][0]=lda(1,4+i,0); a[i][1]=lda(1,4+i,1); }
    stage(false, kt1+2, 0);
    P_MID; mfma_q(4,0); P_END;
    stage(false, kt1+2, 1);
    P_MID; mfma_q(4,2); P_ENDW;
  }

  asm volatile("s_waitcnt vmcnt(0)" ::: "memory");
  __syncthreads();

  if constexpr (sizeof(OutT)==2) {
    ushort* cs = (ushort*)smem;            // [128][264]
    #pragma unroll
    for (int p=0;p<2;++p){
      if (wm == p){
        #pragma unroll
        for (int mf=0;mf<8;++mf)
          #pragma unroll
          for (int nf=0;nf<4;++nf)
            #pragma unroll
            for (int reg=0;reg<4;++reg)
              cs[(mf*16 + ((lane>>4)<<2) + reg)*264 + wn*64 + nf*16 + (lane&15)] = f2bf(acc[mf][nf][reg]);
      }
      __syncthreads();
      #pragma unroll
      for (int it=0; it<8; ++it){
        int ch = tid + it*512;
        int r = ch >> 5, c8 = (ch & 31) * 8;
        int gr = row0 + p*128 + r;
        if (gr < M && col0 + c8 + 8 <= N)
          *(bf16x8*)&((ushort*)C)[(size_t)gr*ldc + col0 + c8] = *(const bf16x8*)&cs[r*264 + c8];
      }
      __syncthreads();
    }
  } else {
    float* cf = (float*)smem;              // [64][260]
    #pragma unroll
    for (int p=0;p<4;++p){
      if (wm == (p>>1)){
        int mh = (p & 1) * 4;
        #pragma unroll
        for (int i=0;i<4;++i)
          #pragma unroll
          for (int nf=0;nf<4;++nf)
            #pragma unroll
            for (int reg=0;reg<4;++reg)
              cf[(i*16 + ((lane>>4)<<2) + reg)*260 + wn*64 + nf*16 + (lane&15)] = acc[mh+i][nf][reg];
      }
      __syncthreads();
      #pragma unroll
      for (int it=0; it<8; ++it){
        int ch = tid + it*512;
        int r = ch >> 6, c4 = (ch & 63) * 4;
        int gr = row0 + p*64 + r, gc = col0 + c4;
        if (gr < M && gc + 4 <= N)
          *(f32x4*)&((float*)C)[(size_t)gr*ldc + gc] = *(const f32x4*)&cf[r*260 + c4];
      }
      __syncthreads();
    }
  }
}

__device__ __forceinline__ void cast_rows2(const float* __restrict__ features,
    ushort* __restrict__ featb, int row_base, int cb){
  int t = threadIdx.x;
  int row = row_base + (cb<<1) + (t>>8);
  int kc = t & 255;
  bf16x8 o;
  if (kc < INDIM/8) {
    const float* p = features + (size_t)row*INDIM + kc*8;
    #pragma unroll
    for (int j=0;j<8;++j) o[j] = (short)f2bf(p[j]);
  } else {
    #pragma unroll
    for (int j=0;j<8;++j) o[j] = 0;
  }
  *(bf16x8*)(featb + (size_t)row*KPAD + kc*8) = o;
}

__device__ __forceinline__ void scan_body(const int* __restrict__ degp,
    int* __restrict__ row_ptr, int* part){
  const int t = threadIdx.x;
  const int base = t * 80;
  int s = 0;
  for (int j=0;j<80;++j){ int i = base+j; s += (i < NNODES) ? degp[i] : 0; }
  part[t] = s;
  __syncthreads();
  for (int off=1; off<512; off<<=1){
    int x = (t >= off) ? part[t-off] : 0;
    __syncthreads();
    part[t] += x;
    __syncthreads();
  }
  int run = (t > 0) ? part[t-1] : 0;
  for (int j=0;j<80;++j){
    int i = base+j;
    if (i <= NNODES){
      row_ptr[i] = run;
      if (i < NNODES) run += degp[i];
    }
  }
}

// conv3 per-node body (wave-per-node, scalar-indexed gather)
__device__ __forceinline__ void conv3_node(int v, int lane,
    const float* __restrict__ h2, const int* __restrict__ row_ptr,
    const int* __restrict__ csr_src, const float* __restrict__ csr_alpha,
    const ushort* __restrict__ W2p, ushort* __restrict__ h3){
  int p0 = __builtin_amdgcn_readfirstlane(row_ptr[v]);
  int p1 = __builtin_amdgcn_readfirstlane(row_ptr[v+1]);
  float accd = 0.f;
  if (lane < ODIM){
    int p = p0;
    for (; p + 4 <= p1; p += 4){
      int s0 = csr_src[p], s1 = csr_src[p+1], s2 = csr_src[p+2], s3 = csr_src[p+3];
      float a0 = csr_alpha[p], a1 = csr_alpha[p+1], a2 = csr_alpha[p+2], a3 = csr_alpha[p+3];
      accd += a0*h2[(size_t)s0*ODIM + lane] + a1*h2[(size_t)s1*ODIM + lane]
            + a2*h2[(size_t)s2*ODIM + lane] + a3*h2[(size_t)s3*ODIM + lane];
    }
    for (; p < p1; ++p)
      accd += csr_alpha[p] * h2[(size_t)csr_src[p]*ODIM + lane];
  }
  float gv[ODIM];
  #pragma unroll
  for (int ci=0; ci<ODIM; ++ci) gv[ci] = __shfl(accd, ci);
  #pragma unroll
  for (int it=0; it<8; ++it){
    int n = it*64 + lane;
    const ushort* wrp = W2p + n*32;
    bf16x8 wvv[4];
    #pragma unroll
    for (int qd=0;qd<4;++qd) wvv[qd] = *(const bf16x8*)(wrp + qd*8);
    float acc = 0.f;
    #pragma unroll
    for (int ci=0; ci<ODIM; ++ci) acc += gv[ci]*bf2f((ushort)wvv[ci>>3][ci&7]);
    acc = acc > 0.f ? acc : __expf(acc)-1.f;
    h3[(size_t)v*HIDD + n] = f2bf(acc);
  }
}

// ---------------- K1: cast part1 | W1 | W2 | hist | W1t pad | cursor+panel_cnt zero -------
#define S1_CAST   10112
#define S1_W1     (S1_CAST + 2000)
#define S1_W2     (S1_W1 + 32)
#define S1_HIST   (S1_W2 + 782)
#define S1_PAD    (S1_HIST + 48)
#define S1_CUR    (S1_PAD + 79)

__global__ __launch_bounds__(512) void setup_kernel(
    const float* __restrict__ features, const float* __restrict__ W1, const float* __restrict__ W2,
    const int* __restrict__ edst,
    ushort* __restrict__ featb, ushort* __restrict__ W1b, ushort* __restrict__ W1t,
    ushort* __restrict__ W2p, ushort* __restrict__ W2tc,
    int* __restrict__ deg, int* __restrict__ cursor, int* __restrict__ panel_cnt){
  int b = blockIdx.x, t = threadIdx.x;
  if (b < S1_CAST){
    cast_rows2(features, featb, 0, b);
  } else if (b < S1_W1){
    int idx = (b - S1_CAST)*512 + t;           // 1,024,000 exactly
    int r = idx >> 9, c = idx & 511;
    ushort bb = f2bf(W1[idx]);
    W1b[idx] = bb;
    W1t[(size_t)c*KPAD + r] = bb;
  } else if (b < S1_W2){
    int idx = (b - S1_W1)*512 + t;             // 16384 exactly
    int k = idx >> 5, c = idx & 31;
    float val = (c < ODIM) ? W2[k*ODIM + c] : 0.f;
    ushort bb = f2bf(val);
    W2p[k*32 + c] = bb;
    W2tc[c*HIDD + k] = bb;
  } else if (b < S1_HIST){
    int e = (b - S1_W2)*512 + t;
    if (e < NEDGES) atomicAdd(&deg[edst[e]], 1);
  } else if (b < S1_PAD){
    int z = (b - S1_HIST)*512 + t;             // 24576 exactly = 512*48
    int c = z / 48, r = 2000 + (z - c*48);
    W1t[(size_t)c*KPAD + r] = 0;
  } else {
    int z = (b - S1_PAD)*512 + t;
    if (z < NNODES) cursor[z] = 0;
    else if (z < NNODES + 157) panel_cnt[z - NNODES] = 0;
  }
}

// ---------------- K2: GEMM1 part1 | scan | cast part2 ----------------
#define K2_G 158
__global__ __launch_bounds__(512, 2) void gemm1a_kernel(
    const ushort* __restrict__ featb, const ushort* __restrict__ W1t, ushort* __restrict__ x1,
    const float* __restrict__ features, ushort* __restrict__ featb_w,
    const int* __restrict__ deg, int* __restrict__ row_ptr){
  __shared__ __align__(16) char smem[131072];
  int b = blockIdx.x;
  if (b < K2_G){
    int s = xcd_swz(b, K2_G);
    int row0 = (s >> 1) << 8;
    int col0 = (s & 1) << 8;
    gemm_body<ushort>(featb, W1t, x1, NNODES, HIDD, KPAD, HIDD, row0, col0, smem);
  } else if (b == K2_G){
    scan_body(deg, row_ptr, (int*)smem);
  } else {
    cast_rows2(features, featb_w, ROWSPLIT, b - K2_G - 1);
  }
}

// ---------------- K3: GEMM1 part2 | place | a_kernel part1 ----------------
#define K3_G 156
#define K3_PL (K3_G + 782)
__global__ __launch_bounds__(512, 2) void gemm1b_kernel(
    const ushort* __restrict__ featb, const ushort* __restrict__ W1t, ushort* __restrict__ x1,
    const int* __restrict__ esrc, const int* __restrict__ edst,
    const int* __restrict__ row_ptr, int* __restrict__ cursor, int* __restrict__ csr_src,
    const float* __restrict__ att_src, const float* __restrict__ att_dst,
    float* __restrict__ a_src, float* __restrict__ a_dst){
  __shared__ __align__(16) char smem[131072];
  int b = blockIdx.x, t = threadIdx.x;
  if (b < K3_G){
    int s = xcd_swz(b, K3_G);
    int row0 = ROWSPLIT + ((s >> 1) << 8);
    int col0 = (s & 1) << 8;
    gemm_body<ushort>(featb, W1t, x1, NNODES, HIDD, KPAD, HIDD, row0, col0, smem);
  } else if (b < K3_PL){
    int e = (b - K3_G)*512 + t;
    if (e < NEDGES){
      int d = edst[e];
      int pos = row_ptr[d] + atomicAdd(&cursor[d], 1);
      csr_src[pos] = esrc[e];
    }
  } else {
    int gid = (b - K3_PL)*512 + t;
    int row = gid >> 6, lane = gid & 63;     // rows [0, ROWSPLIT)
    bf16x8 v = *(const bf16x8*)(x1 + (size_t)row*HIDD + lane*8);
    float ps = 0.f, pd = 0.f;
    #pragma unroll
    for (int j=0;j<8;++j){
      float xv = bf2f((ushort)v[j]);
      ps += xv * att_src[lane*8+j];
      pd += xv * att_dst[lane*8+j];
    }
    #pragma unroll
    for (int off=32; off>0; off>>=1){ ps += __shfl_down(ps, off); pd += __shfl_down(pd, off); }
    if (lane == 0){ a_src[row] = ps; a_dst[row] = pd; }
  }
}

// ---------------- K4: a_kernel part2 ----------------
__global__ __launch_bounds__(512) void a2_kernel(const ushort* __restrict__ x1,
    const float* __restrict__ att_src, const float* __restrict__ att_dst,
    float* __restrict__ a_src, float* __restrict__ a_dst){
  int gid = blockIdx.x*512 + threadIdx.x;
  int row = ROWSPLIT + (gid >> 6), lane = gid & 63;
  if (row >= NNODES) return;
  bf16x8 v = *(const bf16x8*)(x1 + (size_t)row*HIDD + lane*8);
  float ps = 0.f, pd = 0.f;
  #pragma unroll
  for (int j=0;j<8;++j){
    float xv = bf2f((ushort)v[j]);
    ps += xv * att_src[lane*8+j];
    pd += xv * att_dst[lane*8+j];
  }
  #pragma unroll
  for (int off=32; off>0; off>>=1){ ps += __shfl_down(ps, off); pd += __shfl_down(pd, off); }
  if (lane == 0){ a_src[row] = ps; a_dst[row] = pd; }
}

// ---------------- per-node segment softmax over CSR edges (16-lane groups) ----------------
__global__ __launch_bounds__(256) void alpha_kernel(const int* __restrict__ row_ptr,
    const int* __restrict__ csr_src, const float* __restrict__ a_src,
    const float* __restrict__ a_dst, float* __restrict__ csr_alpha){
  int gid = blockIdx.x*256 + threadIdx.x;
  int v = gid >> 4, lane = gid & 15;
  if (v >= NNODES) return;
  int p0 = row_ptr[v], p1 = row_ptr[v+1];
  if (p0 >= p1) return;
  float ad = a_dst[v];
  float m = -1e30f;
  for (int p = p0 + lane; p < p1; p += 16){
    float s = 1.f/(1.f + __expf(-(a_src[csr_src[p]] + ad)));
    m = fmaxf(m, s);
  }
  #pragma unroll
  for (int off=8; off>0; off>>=1) m = fmaxf(m, __shfl_xor(m, off));
  float sum = 0.f;
  for (int p = p0 + lane; p < p1; p += 16){
    float s = 1.f/(1.f + __expf(-(a_src[csr_src[p]] + ad)));
    float e = __expf(s - m);
    csr_alpha[p] = e;
    sum += e;
  }
  #pragma unroll
  for (int off=8; off>0; off>>=1) sum += __shfl_xor(sum, off);
  float inv = 1.f/(sum + 1e-16f);
  for (int p = p0 + lane; p < p1; p += 16) csr_alpha[p] *= inv;
}

// ---------------- conv1 aggregate: pure scalar-indexed gather ----------
__global__ __launch_bounds__(256) void agg1_kernel(const ushort* __restrict__ X,
    const int* __restrict__ row_ptr, const int* __restrict__ csr_src,
    const float* __restrict__ csr_alpha, ushort* __restrict__ outb){
  int gid = blockIdx.x*256 + threadIdx.x;
  int v = gid >> 6, lane = gid & 63;
  if (v >= NNODES) return;
  int p0 = __builtin_amdgcn_readfirstlane(row_ptr[v]);
  int p1 = __builtin_amdgcn_readfirstlane(row_ptr[v+1]);
  float acc[8] = {0.f,0.f,0.f,0.f,0.f,0.f,0.f,0.f};
  int p = p0;
  for (; p + 8 <= p1; p += 8){
    int s[8]; float A[8];
    #pragma unroll
    for (int u=0;u<8;++u){ s[u] = csr_src[p+u]; A[u] = csr_alpha[p+u]; }
    bf16x8 x[8];
    #pragma unroll
    for (int u=0;u<8;++u) x[u] = *(const bf16x8*)(X + (size_t)s[u]*HIDD + lane*8);
    #pragma unroll
    for (int u=0;u<8;++u)
      #pragma unroll
      for (int k=0;k<8;++k) acc[k] += A[u] * bf2f((ushort)x[u][k]);
  }
  for (; p + 4 <= p1; p += 4){
    int s0 = csr_src[p], s1 = csr_src[p+1], s2 = csr_src[p+2], s3 = csr_src[p+3];
    float A0 = csr_alpha[p], A1 = csr_alpha[p+1], A2 = csr_alpha[p+2], A3 = csr_alpha[p+3];
    bf16x8 x0 = *(const bf16x8*)(X + (size_t)s0*HIDD + lane*8);
    bf16x8 x1 = *(const bf16x8*)(X + (size_t)s1*HIDD + lane*8);
    bf16x8 x2 = *(const bf16x8*)(X + (size_t)s2*HIDD + lane*8);
    bf16x8 x3 = *(const bf16x8*)(X + (size_t)s3*HIDD + lane*8);
    #pragma unroll
    for (int k=0;k<8;++k)
      acc[k] += A0*bf2f((ushort)x0[k]) + A1*bf2f((ushort)x1[k])
              + A2*bf2f((ushort)x2[k]) + A3*bf2f((ushort)x3[k]);
  }
  for (; p < p1; ++p){
    int sj = csr_src[p];
    float aj = csr_alpha[p];
    bf16x8 xv = *(const bf16x8*)(X + (size_t)sj*HIDD + lane*8);
    #pragma unroll
    for (int k=0;k<8;++k) acc[k] += aj * bf2f((ushort)xv[k]);
  }
  bf16x8 o;
  #pragma unroll
  for (int k=0;k<8;++k){
    float a = acc[k];
    a = a > 0.f ? a : __expf(a)-1.f;
    o[k] = (short)f2bf(a);
  }
  *(bf16x8*)(outb + (size_t)v*HIDD + lane*8) = o;
}

// ---------------- h2 = h1 @ W2 (K=512, N=30) ----------------
__global__ __launch_bounds__(256) void mid_kernel(const ushort* __restrict__ h1,
    const ushort* __restrict__ W2tc, float* __restrict__ h2){
  __shared__ ushort h1s[32*512];
  __shared__ ushort w2s[32*512];
  const int t = threadIdx.x;
  const int row0 = blockIdx.x * 32;
  const ushort* g = h1 + (size_t)row0*HIDD;
  #pragma unroll
  for (int it=0; it<8; ++it){
    int ch = t + it*256;
    *(bf16x8*)&h1s[ch*8] = *(const bf16x8*)&g[ch*8];
    *(bf16x8*)&w2s[ch*8] = *(const bf16x8*)&W2tc[ch*8];
  }
  __syncthreads();
  int c = t & 31, rg = t >> 5;
  if (c < ODIM){
    float acc[4] = {0.f,0.f,0.f,0.f};
    for (int k0=0;k0<64;++k0){
      bf16x8 wv = *(const bf16x8*)&w2s[c*512 + k0*8];
      #pragma unroll
      for (int rr=0; rr<4; ++rr){
        bf16x8 hv = *(const bf16x8*)&h1s[(rg*4+rr)*HIDD + k0*8];
        #pragma unroll
        for (int j=0;j<8;++j) acc[rr] += bf2f((ushort)hv[j]) * bf2f((ushort)wv[j]);
      }
    }
    #pragma unroll
    for (int rr=0;rr<4;++rr) h2[(size_t)(row0 + rg*4 + rr)*ODIM + c] = acc[rr];
  }
}

// ---------------- fused conv3 + GEMM4: block g does conv3 for nodes [32g,32g+32) ----------
// (exactly the h3 panel g>>3 its own GEMM tile needs), then flag-syncs with its 7 siblings.
__global__ __launch_bounds__(512, 2) void conv3_gemm4_kernel(
    const float* __restrict__ h2, const int* __restrict__ row_ptr,
    const int* __restrict__ csr_src, const float* __restrict__ csr_alpha,
    const ushort* __restrict__ W2p, ushort* __restrict__ h3,
    const ushort* __restrict__ W1b, float* __restrict__ h4,
    int* __restrict__ panel_cnt){
  __shared__ __align__(16) char smem[131072];
  const int g = blockIdx.x, tid = threadIdx.x;
  const int lane = tid & 63, wv = tid >> 6;
  // conv3 chunk
  #pragma unroll
  for (int i=0;i<4;++i){
    int v = 32*g + wv*4 + i;
    if (v < NNODES) conv3_node(v, lane, h2, row_ptr, csr_src, csr_alpha, W2p, h3);
  }
  __threadfence();
  __syncthreads();
  if (tid == 0){
    atomicAdd(&panel_cnt[g >> 3], 1);
    while (atomicAdd(&panel_cnt[g >> 3], 0) < 8) __builtin_amdgcn_s_sleep(2);
  }
  __syncthreads();
  __threadfence();
  int row0 = (g >> 3) << 8;
  int col0 = (g & 7) << 8;
  gemm_body<float>(h3, W1b, h4, NNODES, INDIM, HIDD, INDIM, row0, col0, smem);
}

extern "C" void kernel_launch(void* const* d_in, const int* in_sizes, int n_in,
                              void* d_out, int out_size, void* d_ws, size_t ws_size,
                              hipStream_t stream){
  const float* features = (const float*)d_in[0];
  const float* W1 = (const float*)d_in[1];
  const float* W2 = (const float*)d_in[2];
  const float* att_src = (const float*)d_in[3];
  const float* att_dst = (const float*)d_in[4];
  const int* edge = (const int*)d_in[5];
  const int* esrc = edge;
  const int* edst = edge + NEDGES;

  float* h2 = (float*)d_out;                              // [40000][30]
  float* h4 = h2 + (size_t)NNODES*ODIM;                   // [40000][2000]
  char* obase = (char*)h4;                                // scratch until GEMM4
  ushort* featb = (ushort*)obase;                         // [40000][2048] bf16
  ushort* x1b   = (ushort*)(obase + 163840000);           // [40000][512]
  ushort* h1b   = (ushort*)(obase + 204800000);

  char* wbase = (char*)d_ws;
  size_t o = 0;
  auto walloc = [&](size_t bytes)->void*{ void* p = wbase + o; o += (bytes + 255) & ~(size_t)255; return p; };
  ushort* h3b      = (ushort*)walloc((size_t)NNODES*HIDD*2);
  ushort* W1b      = (ushort*)walloc((size_t)INDIM*HIDD*2);
  ushort* W1t      = (ushort*)walloc((size_t)HIDD*KPAD*2);
  ushort* W2p      = (ushort*)walloc(512*32*2);
  ushort* W2tc     = (ushort*)walloc(32*512*2);
  float*  a_src    = (float*)walloc(NNODES*4);
  float*  a_dst    = (float*)walloc(NNODES*4);
  int*    deg      = (int*)walloc(NNODES*4);
  int*    cursor   = (int*)walloc(NNODES*4);
  int*    row_ptr  = (int*)walloc((NNODES+1)*4);
  int*    csr_src  = (int*)walloc(NEDGES*4);
  float*  csr_alpha= (float*)walloc(NEDGES*4);
  int*    panel_cnt= (int*)walloc(157*4);

  hipMemsetAsync(deg, 0, NNODES*4, stream);

  setup_kernel<<<S1_CUR, 512, 0, stream>>>(features, W1, W2, edst,
      featb, W1b, W1t, W2p, W2tc, deg, cursor, panel_cnt);

  // K2: GEMM1 rows [0, 20224) || scan || cast rows [20224, 40000)
  gemm1a_kernel<<<K2_G + 1 + 9888, 512, 0, stream>>>(featb, W1t, x1b,
      features, featb, deg, row_ptr);

  // K3: GEMM1 rows [20224, 40000) || place || a rows [0, 20224)
  gemm1b_kernel<<<K3_PL + 2528, 512, 0, stream>>>(featb, W1t, x1b,
      esrc, edst, row_ptr, cursor, csr_src, att_src, att_dst, a_src, a_dst);

  a2_kernel<<<2472, 512, 0, stream>>>(x1b, att_src, att_dst, a_src, a_dst);

  alpha_kernel<<<2500, 256, 0, stream>>>(row_ptr, csr_src, a_src, a_dst, csr_alpha);

  agg1_kernel<<<10000, 256, 0, stream>>>(x1b, row_ptr, csr_src, csr_alpha, h1b);
  mid_kernel<<<NNODES/32, 256, 0, stream>>>(h1b, W2tc, h2);

  // fused conv3 + GEMM4 (1256 blocks; per-panel flag sync)
  conv3_gemm4_kernel<<<1256, 512, 0, stream>>>(h2, row_ptr, csr_src, csr_alpha,
      W2p, h3b, W1b, h4, panel_cnt);
}

// Round 14
// 570.881 us; speedup vs baseline: 1.9186x; 1.9186x over previous
//
#include <hip/hip_runtime.h>
#include <cstdint>

#define NNODES 40000
#define INDIM 2000
#define HIDD 512
#define ODIM 30
#define NEDGES 400000
#define KPAD 2048
#define ROWSPLIT 20224              // 79 panels of 256

typedef short bf16x8 __attribute__((ext_vector_type(8)));
typedef float f32x4 __attribute__((ext_vector_type(4)));

__device__ __forceinline__ float bf2f(ushort u){ union{unsigned int i; float f;} x; x.i = ((unsigned int)u)<<16; return x.f; }
__device__ __forceinline__ ushort f2bf(float v){ union{float f; unsigned int u;} x; x.f=v; unsigned int r = x.u + 0x7fffu + ((x.u>>16)&1u); return (ushort)(r>>16); }

__device__ __forceinline__ int xcd_swz(int orig, int nwg){
  int q = nwg >> 3, r = nwg & 7;
  int xcd = orig & 7;
  int idx = orig >> 3;
  return (xcd < r ? xcd*(q+1) : r*(q+1) + (xcd-r)*q) + idx;
}

// ---------------- proven 8-phase 256x256 GEMM body (round-6 schedule, unchanged) ----------
#define P_MID  asm volatile("" ::: "memory"); __builtin_amdgcn_s_barrier(); \
               asm volatile("s_waitcnt lgkmcnt(0)" ::: "memory"); \
               __builtin_amdgcn_sched_barrier(0); __builtin_amdgcn_s_setprio(1);
#define P_END  __builtin_amdgcn_s_setprio(0); asm volatile("" ::: "memory"); \
               __builtin_amdgcn_s_barrier(); __builtin_amdgcn_sched_barrier(0);
#define P_ENDW __builtin_amdgcn_s_setprio(0); \
               asm volatile("s_waitcnt vmcnt(4)" ::: "memory"); \
               asm volatile("" ::: "memory"); __builtin_amdgcn_s_barrier(); \
               __builtin_amdgcn_sched_barrier(0);

template<typename OutT>
__device__ __forceinline__ void gemm_body(
    const ushort* __restrict__ A, const ushort* __restrict__ Bt,
    OutT* __restrict__ C, int M, int N, int K, int ldc,
    int row0, int col0, char* smem)
{
  ushort* Al = (ushort*)smem;                // [2][256][64]
  ushort* Bl = (ushort*)(smem + 65536);      // [2][256][64]
  const int tid = threadIdx.x;
  const int lane = tid & 63;
  const int w = tid >> 6;
  const int wm = w >> 2, wn = w & 3;         // 2M x 4N
  const int NT = K >> 6;

  f32x4 acc[8][4] = {};
  bf16x8 a[4][2], b[4][2];

  auto stage = [&](bool isA, int kt, int h){
    const ushort* G = isA ? A : Bt;
    int base = isA ? row0 : col0;
    int lim  = isA ? M : N;
    ushort* L = (isA ? Al : Bl) + ((kt & 1) << 14);
    if (kt >= NT) kt -= NT;
    #pragma unroll
    for (int it = 0; it < 2; ++it){
      int ch = tid + (it << 9);
      int rl = (h << 7) + (ch >> 3);
      int cs = ch & 7;
      int gr = base + rl; gr = gr < lim ? gr : lim - 1;
      int gc = (kt << 6) + ((cs ^ (rl & 7)) << 3);
      __builtin_amdgcn_global_load_lds(
        (const __attribute__((address_space(1))) unsigned int*)(G + (size_t)gr*K + gc),
        (__attribute__((address_space(3))) unsigned int*)(L + rl*64 + cs*8), 16, 0, 0);
    }
  };
  auto lda = [&](int buf, int mf, int kk) -> bf16x8 {
    int rl = wm*128 + mf*16 + (lane & 15);
    int ko = kk*32 + ((lane >> 4) << 3);
    return *(const bf16x8*)&Al[(buf << 14) + rl*64 + (ko ^ ((rl & 7) << 3))];
  };
  auto ldb = [&](int buf, int nf, int kk) -> bf16x8 {
    int rl = wn*64 + nf*16 + (lane & 15);
    int ko = kk*32 + ((lane >> 4) << 3);
    return *(const bf16x8*)&Bl[(buf << 14) + rl*64 + (ko ^ ((rl & 7) << 3))];
  };
  auto mfma_q = [&](int mbase, int nbase){
    #pragma unroll
    for (int i=0;i<4;++i)
      #pragma unroll
      for (int j=0;j<2;++j)
        #pragma unroll
        for (int kk=0;kk<2;++kk)
          acc[mbase+i][nbase+j] = __builtin_amdgcn_mfma_f32_16x16x32_bf16(
              a[i][kk], b[nbase+j][kk], acc[mbase+i][nbase+j], 0, 0, 0);
  };

  stage(false, 0, 0); stage(false, 0, 1);
  stage(true , 0, 0); stage(true , 0, 1);
  stage(false, 1, 0); stage(false, 1, 1);
  asm volatile("s_waitcnt vmcnt(4)" ::: "memory");
  asm volatile("" ::: "memory");
  __builtin_amdgcn_s_barrier();
  __builtin_amdgcn_sched_barrier(0);

  const int NT2 = NT >> 1;
  for (int t = 0; t < NT2; ++t){
    const int kt0 = 2*t, kt1 = 2*t + 1;
    #pragma unroll
    for (int i=0;i<4;++i){ a[i][0]=lda(0,i,0); a[i][1]=lda(0,i,1); }
    #pragma unroll
    for (int j=0;j<2;++j){ b[j][0]=ldb(0,j,0); b[j][1]=ldb(0,j,1); }
    stage(true, kt1, 0);
    P_MID; mfma_q(0,0); P_END;
    #pragma unroll
    for (int j=2;j<4;++j){ b[j][0]=ldb(0,j,0); b[j][1]=ldb(0,j,1); }
    stage(true, kt1, 1);
    P_MID; mfma_q(0,2); P_END;
    #pragma unroll
    for (int i=0;i<4;++i){ a[i][0]=lda(0,4+i,0); a[i][1]=lda(0,4+i,1); }
    stage(false, kt0+2, 0);
    P_MID; mfma_q(4,0); P_END;
    stage(false, kt0+2, 1);
    P_MID; mfma_q(4,2); P_ENDW;
    #pragma unroll
    for (int i=0;i<4;++i){ a[i][0]=lda(1,i,0); a[i][1]=lda(1,i,1); }
    #pragma unroll
    for (int j=0;j<2;++j){ b[j][0]=ldb(1,j,0); b[j][1]=ldb(1,j,1); }
    stage(true, kt0+2, 0);
    P_MID; mfma_q(0,0); P_END;
    #pragma unroll
    for (int j=2;j<4;++j){ b[j][0]=ldb(1,j,0); b[j][1]=ldb(1,j,1); }
    stage(true, kt0+2, 1);
    P_MID; mfma_q(0,2); P_END;
    #pragma unroll
    for (int i=0;i<4;++i){ a[i][0]=lda(1,4+i,0); a[i][1]=lda(1,4+i,1); }
    stage(false, kt1+2, 0);
    P_MID; mfma_q(4,0); P_END;
    stage(false, kt1+2, 1);
    P_MID; mfma_q(4,2); P_ENDW;
  }

  asm volatile("s_waitcnt vmcnt(0)" ::: "memory");
  __syncthreads();

  if constexpr (sizeof(OutT)==2) {
    ushort* cs = (ushort*)smem;            // [128][264]
    #pragma unroll
    for (int p=0;p<2;++p){
      if (wm == p){
        #pragma unroll
        for (int mf=0;mf<8;++mf)
          #pragma unroll
          for (int nf=0;nf<4;++nf)
            #pragma unroll
            for (int reg=0;reg<4;++reg)
              cs[(mf*16 + ((lane>>4)<<2) + reg)*264 + wn*64 + nf*16 + (lane&15)] = f2bf(acc[mf][nf][reg]);
      }
      __syncthreads();
      #pragma unroll
      for (int it=0; it<8; ++it){
        int ch = tid + it*512;
        int r = ch >> 5, c8 = (ch & 31) * 8;
        int gr = row0 + p*128 + r;
        if (gr < M && col0 + c8 + 8 <= N)
          *(bf16x8*)&((ushort*)C)[(size_t)gr*ldc + col0 + c8] = *(const bf16x8*)&cs[r*264 + c8];
      }
      __syncthreads();
    }
  } else {
    float* cf = (float*)smem;              // [64][260]
    #pragma unroll
    for (int p=0;p<4;++p){
      if (wm == (p>>1)){
        int mh = (p & 1) * 4;
        #pragma unroll
        for (int i=0;i<4;++i)
          #pragma unroll
          for (int nf=0;nf<4;++nf)
            #pragma unroll
            for (int reg=0;reg<4;++reg)
              cf[(i*16 + ((lane>>4)<<2) + reg)*260 + wn*64 + nf*16 + (lane&15)] = acc[mh+i][nf][reg];
      }
      __syncthreads();
      #pragma unroll
      for (int it=0; it<8; ++it){
        int ch = tid + it*512;
        int r = ch >> 6, c4 = (ch & 63) * 4;
        int gr = row0 + p*64 + r, gc = col0 + c4;
        if (gr < M && gc + 4 <= N)
          __builtin_nontemporal_store(*(const f32x4*)&cf[r*260 + c4],
                                      (f32x4*)&((float*)C)[(size_t)gr*ldc + gc]);
      }
      __syncthreads();
    }
  }
}

__device__ __forceinline__ void cast_rows2(const float* __restrict__ features,
    ushort* __restrict__ featb, int row_base, int cb){
  int t = threadIdx.x;
  int row = row_base + (cb<<1) + (t>>8);
  int kc = t & 255;
  bf16x8 o;
  if (kc < INDIM/8) {
    const float* p = features + (size_t)row*INDIM + kc*8;
    #pragma unroll
    for (int j=0;j<8;++j) o[j] = (short)f2bf(p[j]);
  } else {
    #pragma unroll
    for (int j=0;j<8;++j) o[j] = 0;
  }
  *(bf16x8*)(featb + (size_t)row*KPAD + kc*8) = o;
}

__device__ __forceinline__ void scan_body(const int* __restrict__ degp,
    int* __restrict__ row_ptr, int* part){
  const int t = threadIdx.x;
  const int base = t * 80;
  int s = 0;
  for (int j=0;j<80;++j){ int i = base+j; s += (i < NNODES) ? degp[i] : 0; }
  part[t] = s;
  __syncthreads();
  for (int off=1; off<512; off<<=1){
    int x = (t >= off) ? part[t-off] : 0;
    __syncthreads();
    part[t] += x;
    __syncthreads();
  }
  int run = (t > 0) ? part[t-1] : 0;
  for (int j=0;j<80;++j){
    int i = base+j;
    if (i <= NNODES){
      row_ptr[i] = run;
      if (i < NNODES) run += degp[i];
    }
  }
}

// ---------------- K1: cast part1 | W1 | W2 | hist | W1t pad | cursor zero (512 thr) -------
#define S1_CAST   10112
#define S1_W1     (S1_CAST + 2000)
#define S1_W2     (S1_W1 + 32)
#define S1_HIST   (S1_W2 + 782)
#define S1_PAD    (S1_HIST + 48)
#define S1_CUR    (S1_PAD + 79)

__global__ __launch_bounds__(512) void setup_kernel(
    const float* __restrict__ features, const float* __restrict__ W1, const float* __restrict__ W2,
    const int* __restrict__ edst,
    ushort* __restrict__ featb, ushort* __restrict__ W1b, ushort* __restrict__ W1t,
    ushort* __restrict__ W2p, ushort* __restrict__ W2tc,
    int* __restrict__ deg, int* __restrict__ cursor){
  int b = blockIdx.x, t = threadIdx.x;
  if (b < S1_CAST){
    cast_rows2(features, featb, 0, b);
  } else if (b < S1_W1){
    int idx = (b - S1_CAST)*512 + t;           // 1,024,000 exactly
    int r = idx >> 9, c = idx & 511;
    ushort bb = f2bf(W1[idx]);
    W1b[idx] = bb;
    W1t[(size_t)c*KPAD + r] = bb;
  } else if (b < S1_W2){
    int idx = (b - S1_W1)*512 + t;             // 16384 exactly
    int k = idx >> 5, c = idx & 31;
    float val = (c < ODIM) ? W2[k*ODIM + c] : 0.f;
    ushort bb = f2bf(val);
    W2p[k*32 + c] = bb;
    W2tc[c*HIDD + k] = bb;
  } else if (b < S1_HIST){
    int e = (b - S1_W2)*512 + t;
    if (e < NEDGES) atomicAdd(&deg[edst[e]], 1);
  } else if (b < S1_PAD){
    int z = (b - S1_HIST)*512 + t;             // 24576 exactly = 512*48
    int c = z / 48, r = 2000 + (z - c*48);
    W1t[(size_t)c*KPAD + r] = 0;
  } else {
    int z = (b - S1_PAD)*512 + t;
    if (z < NNODES) cursor[z] = 0;
  }
}

// ---------------- K2: GEMM1 part1 | scan | cast part2 ----------------
#define K2_G 158
__global__ __launch_bounds__(512, 2) void gemm1a_kernel(
    const ushort* __restrict__ featb, const ushort* __restrict__ W1t, ushort* __restrict__ x1,
    const float* __restrict__ features, ushort* __restrict__ featb_w,
    const int* __restrict__ deg, int* __restrict__ row_ptr){
  __shared__ __align__(16) char smem[131072];
  int b = blockIdx.x;
  if (b < K2_G){
    int s = xcd_swz(b, K2_G);
    int row0 = (s >> 1) << 8;
    int col0 = (s & 1) << 8;
    gemm_body<ushort>(featb, W1t, x1, NNODES, HIDD, KPAD, HIDD, row0, col0, smem);
  } else if (b == K2_G){
    scan_body(deg, row_ptr, (int*)smem);
  } else {
    cast_rows2(features, featb_w, ROWSPLIT, b - K2_G - 1);
  }
}

// ---------------- K3: GEMM1 part2 | place | a_kernel part1 ----------------
#define K3_G 156
#define K3_PL (K3_G + 782)
__global__ __launch_bounds__(512, 2) void gemm1b_kernel(
    const ushort* __restrict__ featb, const ushort* __restrict__ W1t, ushort* __restrict__ x1,
    const int* __restrict__ esrc, const int* __restrict__ edst,
    const int* __restrict__ row_ptr, int* __restrict__ cursor, int* __restrict__ csr_src,
    const float* __restrict__ att_src, const float* __restrict__ att_dst,
    float* __restrict__ a_src, float* __restrict__ a_dst){
  __shared__ __align__(16) char smem[131072];
  int b = blockIdx.x, t = threadIdx.x;
  if (b < K3_G){
    int s = xcd_swz(b, K3_G);
    int row0 = ROWSPLIT + ((s >> 1) << 8);
    int col0 = (s & 1) << 8;
    gemm_body<ushort>(featb, W1t, x1, NNODES, HIDD, KPAD, HIDD, row0, col0, smem);
  } else if (b < K3_PL){
    int e = (b - K3_G)*512 + t;
    if (e < NEDGES){
      int d = edst[e];
      int pos = row_ptr[d] + atomicAdd(&cursor[d], 1);
      csr_src[pos] = esrc[e];
    }
  } else {
    int gid = (b - K3_PL)*512 + t;
    int row = gid >> 6, lane = gid & 63;     // rows [0, ROWSPLIT)
    bf16x8 v = *(const bf16x8*)(x1 + (size_t)row*HIDD + lane*8);
    float ps = 0.f, pd = 0.f;
    #pragma unroll
    for (int j=0;j<8;++j){
      float xv = bf2f((ushort)v[j]);
      ps += xv * att_src[lane*8+j];
      pd += xv * att_dst[lane*8+j];
    }
    #pragma unroll
    for (int off=32; off>0; off>>=1){ ps += __shfl_down(ps, off); pd += __shfl_down(pd, off); }
    if (lane == 0){ a_src[row] = ps; a_dst[row] = pd; }
  }
}

// ---------------- K4: a_kernel part2 ----------------
__global__ __launch_bounds__(512) void a2_kernel(const ushort* __restrict__ x1,
    const float* __restrict__ att_src, const float* __restrict__ att_dst,
    float* __restrict__ a_src, float* __restrict__ a_dst){
  int gid = blockIdx.x*512 + threadIdx.x;
  int row = ROWSPLIT + (gid >> 6), lane = gid & 63;
  if (row >= NNODES) return;
  bf16x8 v = *(const bf16x8*)(x1 + (size_t)row*HIDD + lane*8);
  float ps = 0.f, pd = 0.f;
  #pragma unroll
  for (int j=0;j<8;++j){
    float xv = bf2f((ushort)v[j]);
    ps += xv * att_src[lane*8+j];
    pd += xv * att_dst[lane*8+j];
  }
  #pragma unroll
  for (int off=32; off>0; off>>=1){ ps += __shfl_down(ps, off); pd += __shfl_down(pd, off); }
  if (lane == 0){ a_src[row] = ps; a_dst[row] = pd; }
}

// ---------------- per-node segment softmax over CSR edges (16-lane groups) ----------------
__global__ __launch_bounds__(256) void alpha_kernel(const int* __restrict__ row_ptr,
    const int* __restrict__ csr_src, const float* __restrict__ a_src,
    const float* __restrict__ a_dst, float* __restrict__ csr_alpha){
  int gid = blockIdx.x*256 + threadIdx.x;
  int v = gid >> 4, lane = gid & 15;
  if (v >= NNODES) return;
  int p0 = row_ptr[v], p1 = row_ptr[v+1];
  if (p0 >= p1) return;
  float ad = a_dst[v];
  float m = -1e30f;
  for (int p = p0 + lane; p < p1; p += 16){
    float s = 1.f/(1.f + __expf(-(a_src[csr_src[p]] + ad)));
    m = fmaxf(m, s);
  }
  #pragma unroll
  for (int off=8; off>0; off>>=1) m = fmaxf(m, __shfl_xor(m, off));
  float sum = 0.f;
  for (int p = p0 + lane; p < p1; p += 16){
    float s = 1.f/(1.f + __expf(-(a_src[csr_src[p]] + ad)));
    float e = __expf(s - m);
    csr_alpha[p] = e;
    sum += e;
  }
  #pragma unroll
  for (int off=8; off>0; off>>=1) sum += __shfl_xor(sum, off);
  float inv = 1.f/(sum + 1e-16f);
  for (int p = p0 + lane; p < p1; p += 16) csr_alpha[p] *= inv;
}

// ---------------- conv1 aggregate: pure scalar-indexed gather ----------
__global__ __launch_bounds__(256) void agg1_kernel(const ushort* __restrict__ X,
    const int* __restrict__ row_ptr, const int* __restrict__ csr_src,
    const float* __restrict__ csr_alpha, ushort* __restrict__ outb){
  int gid = blockIdx.x*256 + threadIdx.x;
  int v = gid >> 6, lane = gid & 63;
  if (v >= NNODES) return;
  int p0 = __builtin_amdgcn_readfirstlane(row_ptr[v]);
  int p1 = __builtin_amdgcn_readfirstlane(row_ptr[v+1]);
  float acc[8] = {0.f,0.f,0.f,0.f,0.f,0.f,0.f,0.f};
  int p = p0;
  for (; p + 8 <= p1; p += 8){
    int s[8]; float A[8];
    #pragma unroll
    for (int u=0;u<8;++u){ s[u] = csr_src[p+u]; A[u] = csr_alpha[p+u]; }
    bf16x8 x[8];
    #pragma unroll
    for (int u=0;u<8;++u) x[u] = *(const bf16x8*)(X + (size_t)s[u]*HIDD + lane*8);
    #pragma unroll
    for (int u=0;u<8;++u)
      #pragma unroll
      for (int k=0;k<8;++k) acc[k] += A[u] * bf2f((ushort)x[u][k]);
  }
  for (; p + 4 <= p1; p += 4){
    int s0 = csr_src[p], s1 = csr_src[p+1], s2 = csr_src[p+2], s3 = csr_src[p+3];
    float A0 = csr_alpha[p], A1 = csr_alpha[p+1], A2 = csr_alpha[p+2], A3 = csr_alpha[p+3];
    bf16x8 x0 = *(const bf16x8*)(X + (size_t)s0*HIDD + lane*8);
    bf16x8 x1 = *(const bf16x8*)(X + (size_t)s1*HIDD + lane*8);
    bf16x8 x2 = *(const bf16x8*)(X + (size_t)s2*HIDD + lane*8);
    bf16x8 x3 = *(const bf16x8*)(X + (size_t)s3*HIDD + lane*8);
    #pragma unroll
    for (int k=0;k<8;++k)
      acc[k] += A0*bf2f((ushort)x0[k]) + A1*bf2f((ushort)x1[k])
              + A2*bf2f((ushort)x2[k]) + A3*bf2f((ushort)x3[k]);
  }
  for (; p < p1; ++p){
    int sj = csr_src[p];
    float aj = csr_alpha[p];
    bf16x8 xv = *(const bf16x8*)(X + (size_t)sj*HIDD + lane*8);
    #pragma unroll
    for (int k=0;k<8;++k) acc[k] += aj * bf2f((ushort)xv[k]);
  }
  bf16x8 o;
  #pragma unroll
  for (int k=0;k<8;++k){
    float a = acc[k];
    a = a > 0.f ? a : __expf(a)-1.f;
    o[k] = (short)f2bf(a);
  }
  *(bf16x8*)(outb + (size_t)v*HIDD + lane*8) = o;
}

// ---------------- h2 = h1 @ W2 (K=512, N=30) ----------------
__global__ __launch_bounds__(256) void mid_kernel(const ushort* __restrict__ h1,
    const ushort* __restrict__ W2tc, float* __restrict__ h2){
  __shared__ ushort h1s[32*512];
  __shared__ ushort w2s[32*512];
  const int t = threadIdx.x;
  const int row0 = blockIdx.x * 32;
  const ushort* g = h1 + (size_t)row0*HIDD;
  #pragma unroll
  for (int it=0; it<8; ++it){
    int ch = t + it*256;
    *(bf16x8*)&h1s[ch*8] = *(const bf16x8*)&g[ch*8];
    *(bf16x8*)&w2s[ch*8] = *(const bf16x8*)&W2tc[ch*8];
  }
  __syncthreads();
  int c = t & 31, rg = t >> 5;
  if (c < ODIM){
    float acc[4] = {0.f,0.f,0.f,0.f};
    for (int k0=0;k0<64;++k0){
      bf16x8 wv = *(const bf16x8*)&w2s[c*512 + k0*8];
      #pragma unroll
      for (int rr=0; rr<4; ++rr){
        bf16x8 hv = *(const bf16x8*)&h1s[(rg*4+rr)*HIDD + k0*8];
        #pragma unroll
        for (int j=0;j<8;++j) acc[rr] += bf2f((ushort)hv[j]) * bf2f((ushort)wv[j]);
      }
    }
    #pragma unroll
    for (int rr=0;rr<4;++rr) h2[(size_t)(row0 + rg*4 + rr)*ODIM + c] = acc[rr];
  }
}

// ---------------- conv3 fused: g[v]=sum alpha*h2[src]; h3=elu(g @ W2^T) -----
__global__ __launch_bounds__(256) void conv3_kernel(const float* __restrict__ h2,
    const int* __restrict__ row_ptr, const int* __restrict__ csr_src,
    const float* __restrict__ csr_alpha, const ushort* __restrict__ W2p,
    ushort* __restrict__ h3){
  int gid = blockIdx.x*256 + threadIdx.x;
  int v = gid >> 6, lane = gid & 63;
  if (v >= NNODES) return;
  int p0 = __builtin_amdgcn_readfirstlane(row_ptr[v]);
  int p1 = __builtin_amdgcn_readfirstlane(row_ptr[v+1]);
  float accd = 0.f;
  if (lane < ODIM){
    int p = p0;
    for (; p + 4 <= p1; p += 4){
      int s0 = csr_src[p], s1 = csr_src[p+1], s2 = csr_src[p+2], s3 = csr_src[p+3];
      float a0 = csr_alpha[p], a1 = csr_alpha[p+1], a2 = csr_alpha[p+2], a3 = csr_alpha[p+3];
      accd += a0*h2[(size_t)s0*ODIM + lane] + a1*h2[(size_t)s1*ODIM + lane]
            + a2*h2[(size_t)s2*ODIM + lane] + a3*h2[(size_t)s3*ODIM + lane];
    }
    for (; p < p1; ++p)
      accd += csr_alpha[p] * h2[(size_t)csr_src[p]*ODIM + lane];
  }
  float gv[ODIM];
  #pragma unroll
  for (int ci=0; ci<ODIM; ++ci) gv[ci] = __shfl(accd, ci);
  #pragma unroll
  for (int it=0; it<8; ++it){
    int n = it*64 + lane;
    const ushort* wrp = W2p + n*32;
    bf16x8 wvv[4];
    #pragma unroll
    for (int qd=0;qd<4;++qd) wvv[qd] = *(const bf16x8*)(wrp + qd*8);
    float acc = 0.f;
    #pragma unroll
    for (int ci=0; ci<ODIM; ++ci) acc += gv[ci]*bf2f((ushort)wvv[ci>>3][ci&7]);
    acc = acc > 0.f ? acc : __expf(acc)-1.f;
    h3[(size_t)v*HIDD + n] = f2bf(acc);
  }
}

// ---------------- GEMM4 ----------------
template<typename OutT>
__global__ __launch_bounds__(512, 2) void gemm8_kernel(
    const ushort* __restrict__ A, const ushort* __restrict__ Bt,
    OutT* __restrict__ C, int M, int N, int K, int ldc, int nwg, int cshift)
{
  __shared__ __align__(16) char smem[131072];
  int s = xcd_swz(blockIdx.x, nwg);
  int row0 = (s >> cshift) << 8;
  int col0 = (s & ((1 << cshift) - 1)) << 8;
  gemm_body<OutT>(A, Bt, C, M, N, K, ldc, row0, col0, smem);
}

extern "C" void kernel_launch(void* const* d_in, const int* in_sizes, int n_in,
                              void* d_out, int out_size, void* d_ws, size_t ws_size,
                              hipStream_t stream){
  const float* features = (const float*)d_in[0];
  const float* W1 = (const float*)d_in[1];
  const float* W2 = (const float*)d_in[2];
  const float* att_src = (const float*)d_in[3];
  const float* att_dst = (const float*)d_in[4];
  const int* edge = (const int*)d_in[5];
  const int* esrc = edge;
  const int* edst = edge + NEDGES;

  float* h2 = (float*)d_out;                              // [40000][30]
  float* h4 = h2 + (size_t)NNODES*ODIM;                   // [40000][2000]
  char* obase = (char*)h4;                                // scratch until GEMM4
  ushort* featb = (ushort*)obase;                         // [40000][2048] bf16
  ushort* x1b   = (ushort*)(obase + 163840000);           // [40000][512]
  ushort* h1b   = (ushort*)(obase + 204800000);

  char* wbase = (char*)d_ws;
  size_t o = 0;
  auto walloc = [&](size_t bytes)->void*{ void* p = wbase + o; o += (bytes + 255) & ~(size_t)255; return p; };
  ushort* h3b      = (ushort*)walloc((size_t)NNODES*HIDD*2);
  ushort* W1b      = (ushort*)walloc((size_t)INDIM*HIDD*2);
  ushort* W1t      = (ushort*)walloc((size_t)HIDD*KPAD*2);
  ushort* W2p      = (ushort*)walloc(512*32*2);
  ushort* W2tc     = (ushort*)walloc(32*512*2);
  float*  a_src    = (float*)walloc(NNODES*4);
  float*  a_dst    = (float*)walloc(NNODES*4);
  int*    deg      = (int*)walloc(NNODES*4);
  int*    cursor   = (int*)walloc(NNODES*4);
  int*    row_ptr  = (int*)walloc((NNODES+1)*4);
  int*    csr_src  = (int*)walloc(NEDGES*4);
  float*  csr_alpha= (float*)walloc(NEDGES*4);

  hipMemsetAsync(deg, 0, NNODES*4, stream);

  setup_kernel<<<S1_CUR, 512, 0, stream>>>(features, W1, W2, edst,
      featb, W1b, W1t, W2p, W2tc, deg, cursor);

  // K2: GEMM1 rows [0, 20224) || scan || cast rows [20224, 40000)
  gemm1a_kernel<<<K2_G + 1 + 9888, 512, 0, stream>>>(featb, W1t, x1b,
      features, featb, deg, row_ptr);

  // K3: GEMM1 rows [20224, 40000) || place || a rows [0, 20224)
  gemm1b_kernel<<<K3_PL + 2528, 512, 0, stream>>>(featb, W1t, x1b,
      esrc, edst, row_ptr, cursor, csr_src, att_src, att_dst, a_src, a_dst);

  a2_kernel<<<2472, 512, 0, stream>>>(x1b, att_src, att_dst, a_src, a_dst);

  alpha_kernel<<<2500, 256, 0, stream>>>(row_ptr, csr_src, a_src, a_dst, csr_alpha);

  agg1_kernel<<<10000, 256, 0, stream>>>(x1b, row_ptr, csr_src, csr_alpha, h1b);
  mid_kernel<<<NNODES/32, 256, 0, stream>>>(h1b, W2tc, h2);
  conv3_kernel<<<10000, 256, 0, stream>>>(h2, row_ptr, csr_src, csr_alpha, W2p, h3b);
  gemm8_kernel<float><<<1256, 512, 0, stream>>>(h3b, W1b, h4,
      NNODES, INDIM, HIDD, INDIM, 1256, 3);
}

// Round 15
// 570.462 us; speedup vs baseline: 1.9200x; 1.0007x over previous
//
#include <hip/hip_runtime.h>
#include <cstdint>

#define NNODES 40000
#define INDIM 2000
#define HIDD 512
#define ODIM 30
#define NEDGES 400000
#define KPAD 2048
#define ROWSPLIT 20224              // 79 panels of 256 (GEMM1 split)
#define ASPLIT 20480                // alpha/agg1 overlap split

typedef short bf16x8 __attribute__((ext_vector_type(8)));
typedef float f32x4 __attribute__((ext_vector_type(4)));

__device__ __forceinline__ float bf2f(ushort u){ union{unsigned int i; float f;} x; x.i = ((unsigned int)u)<<16; return x.f; }
__device__ __forceinline__ ushort f2bf(float v){ union{float f; unsigned int u;} x; x.f=v; unsigned int r = x.u + 0x7fffu + ((x.u>>16)&1u); return (ushort)(r>>16); }

__device__ __forceinline__ int xcd_swz(int orig, int nwg){
  int q = nwg >> 3, r = nwg & 7;
  int xcd = orig & 7;
  int idx = orig >> 3;
  return (xcd < r ? xcd*(q+1) : r*(q+1) + (xcd-r)*q) + idx;
}

// ---------------- proven 8-phase 256x256 GEMM body (round-6 schedule, unchanged) ----------
#define P_MID  asm volatile("" ::: "memory"); __builtin_amdgcn_s_barrier(); \
               asm volatile("s_waitcnt lgkmcnt(0)" ::: "memory"); \
               __builtin_amdgcn_sched_barrier(0); __builtin_amdgcn_s_setprio(1);
#define P_END  __builtin_amdgcn_s_setprio(0); asm volatile("" ::: "memory"); \
               __builtin_amdgcn_s_barrier(); __builtin_amdgcn_sched_barrier(0);
#define P_ENDW __builtin_amdgcn_s_setprio(0); \
               asm volatile("s_waitcnt vmcnt(4)" ::: "memory"); \
               asm volatile("" ::: "memory"); __builtin_amdgcn_s_barrier(); \
               __builtin_amdgcn_sched_barrier(0);

template<typename OutT>
__device__ __forceinline__ void gemm_body(
    const ushort* __restrict__ A, const ushort* __restrict__ Bt,
    OutT* __restrict__ C, int M, int N, int K, int ldc,
    int row0, int col0, char* smem)
{
  ushort* Al = (ushort*)smem;                // [2][256][64]
  ushort* Bl = (ushort*)(smem + 65536);      // [2][256][64]
  const int tid = threadIdx.x;
  const int lane = tid & 63;
  const int w = tid >> 6;
  const int wm = w >> 2, wn = w & 3;         // 2M x 4N
  const int NT = K >> 6;

  f32x4 acc[8][4] = {};
  bf16x8 a[4][2], b[4][2];

  auto stage = [&](bool isA, int kt, int h){
    const ushort* G = isA ? A : Bt;
    int base = isA ? row0 : col0;
    int lim  = isA ? M : N;
    ushort* L = (isA ? Al : Bl) + ((kt & 1) << 14);
    if (kt >= NT) kt -= NT;
    #pragma unroll
    for (int it = 0; it < 2; ++it){
      int ch = tid + (it << 9);
      int rl = (h << 7) + (ch >> 3);
      int cs = ch & 7;
      int gr = base + rl; gr = gr < lim ? gr : lim - 1;
      int gc = (kt << 6) + ((cs ^ (rl & 7)) << 3);
      __builtin_amdgcn_global_load_lds(
        (const __attribute__((address_space(1))) unsigned int*)(G + (size_t)gr*K + gc),
        (__attribute__((address_space(3))) unsigned int*)(L + rl*64 + cs*8), 16, 0, 0);
    }
  };
  auto lda = [&](int buf, int mf, int kk) -> bf16x8 {
    int rl = wm*128 + mf*16 + (lane & 15);
    int ko = kk*32 + ((lane >> 4) << 3);
    return *(const bf16x8*)&Al[(buf << 14) + rl*64 + (ko ^ ((rl & 7) << 3))];
  };
  auto ldb = [&](int buf, int nf, int kk) -> bf16x8 {
    int rl = wn*64 + nf*16 + (lane & 15);
    int ko = kk*32 + ((lane >> 4) << 3);
    return *(const bf16x8*)&Bl[(buf << 14) + rl*64 + (ko ^ ((rl & 7) << 3))];
  };
  auto mfma_q = [&](int mbase, int nbase){
    #pragma unroll
    for (int i=0;i<4;++i)
      #pragma unroll
      for (int j=0;j<2;++j)
        #pragma unroll
        for (int kk=0;kk<2;++kk)
          acc[mbase+i][nbase+j] = __builtin_amdgcn_mfma_f32_16x16x32_bf16(
              a[i][kk], b[nbase+j][kk], acc[mbase+i][nbase+j], 0, 0, 0);
  };

  stage(false, 0, 0); stage(false, 0, 1);
  stage(true , 0, 0); stage(true , 0, 1);
  stage(false, 1, 0); stage(false, 1, 1);
  asm volatile("s_waitcnt vmcnt(4)" ::: "memory");
  asm volatile("" ::: "memory");
  __builtin_amdgcn_s_barrier();
  __builtin_amdgcn_sched_barrier(0);

  const int NT2 = NT >> 1;
  for (int t = 0; t < NT2; ++t){
    const int kt0 = 2*t, kt1 = 2*t + 1;
    #pragma unroll
    for (int i=0;i<4;++i){ a[i][0]=lda(0,i,0); a[i][1]=lda(0,i,1); }
    #pragma unroll
    for (int j=0;j<2;++j){ b[j][0]=ldb(0,j,0); b[j][1]=ldb(0,j,1); }
    stage(true, kt1, 0);
    P_MID; mfma_q(0,0); P_END;
    #pragma unroll
    for (int j=2;j<4;++j){ b[j][0]=ldb(0,j,0); b[j][1]=ldb(0,j,1); }
    stage(true, kt1, 1);
    P_MID; mfma_q(0,2); P_END;
    #pragma unroll
    for (int i=0;i<4;++i){ a[i][0]=lda(0,4+i,0); a[i][1]=lda(0,4+i,1); }
    stage(false, kt0+2, 0);
    P_MID; mfma_q(4,0); P_END;
    stage(false, kt0+2, 1);
    P_MID; mfma_q(4,2); P_ENDW;
    #pragma unroll
    for (int i=0;i<4;++i){ a[i][0]=lda(1,i,0); a[i][1]=lda(1,i,1); }
    #pragma unroll
    for (int j=0;j<2;++j){ b[j][0]=ldb(1,j,0); b[j][1]=ldb(1,j,1); }
    stage(true, kt0+2, 0);
    P_MID; mfma_q(0,0); P_END;
    #pragma unroll
    for (int j=2;j<4;++j){ b[j][0]=ldb(1,j,0); b[j][1]=ldb(1,j,1); }
    stage(true, kt0+2, 1);
    P_MID; mfma_q(0,2); P_END;
    #pragma unroll
    for (int i=0;i<4;++i){ a[i][0]=lda(1,4+i,0); a[i][1]=lda(1,4+i,1); }
    stage(false, kt1+2, 0);
    P_MID; mfma_q(4,0); P_END;
    stage(false, kt1+2, 1);
    P_MID; mfma_q(4,2); P_ENDW;
  }

  asm volatile("s_waitcnt vmcnt(0)" ::: "memory");
  __syncthreads();

  if constexpr (sizeof(OutT)==2) {
    ushort* cs = (ushort*)smem;            // [128][264]
    #pragma unroll
    for (int p=0;p<2;++p){
      if (wm == p){
        #pragma unroll
        for (int mf=0;mf<8;++mf)
          #pragma unroll
          for (int nf=0;nf<4;++nf)
            #pragma unroll
            for (int reg=0;reg<4;++reg)
              cs[(mf*16 + ((lane>>4)<<2) + reg)*264 + wn*64 + nf*16 + (lane&15)] = f2bf(acc[mf][nf][reg]);
      }
      __syncthreads();
      #pragma unroll
      for (int it=0; it<8; ++it){
        int ch = tid + it*512;
        int r = ch >> 5, c8 = (ch & 31) * 8;
        int gr = row0 + p*128 + r;
        if (gr < M && col0 + c8 + 8 <= N)
          *(bf16x8*)&((ushort*)C)[(size_t)gr*ldc + col0 + c8] = *(const bf16x8*)&cs[r*264 + c8];
      }
      __syncthreads();
    }
  } else {
    float* cf = (float*)smem;              // [64][260]
    #pragma unroll
    for (int p=0;p<4;++p){
      if (wm == (p>>1)){
        int mh = (p & 1) * 4;
        #pragma unroll
        for (int i=0;i<4;++i)
          #pragma unroll
          for (int nf=0;nf<4;++nf)
            #pragma unroll
            for (int reg=0;reg<4;++reg)
              cf[(i*16 + ((lane>>4)<<2) + reg)*260 + wn*64 + nf*16 + (lane&15)] = acc[mh+i][nf][reg];
      }
      __syncthreads();
      #pragma unroll
      for (int it=0; it<8; ++it){
        int ch = tid + it*512;
        int r = ch >> 6, c4 = (ch & 63) * 4;
        int gr = row0 + p*64 + r, gc = col0 + c4;
        if (gr < M && gc + 4 <= N)
          __builtin_nontemporal_store(*(const f32x4*)&cf[r*260 + c4],
                                      (f32x4*)&((float*)C)[(size_t)gr*ldc + gc]);
      }
      __syncthreads();
    }
  }
}

__device__ __forceinline__ void cast_rows2(const float* __restrict__ features,
    ushort* __restrict__ featb, int row_base, int cb){
  int t = threadIdx.x;
  int row = row_base + (cb<<1) + (t>>8);
  int kc = t & 255;
  bf16x8 o;
  if (kc < INDIM/8) {
    const f32x4* p = (const f32x4*)(features + (size_t)row*INDIM + kc*8);
    f32x4 lo = __builtin_nontemporal_load(p);
    f32x4 hi = __builtin_nontemporal_load(p+1);
    #pragma unroll
    for (int j=0;j<4;++j) o[j] = (short)f2bf(lo[j]);
    #pragma unroll
    for (int j=0;j<4;++j) o[4+j] = (short)f2bf(hi[j]);
  } else {
    #pragma unroll
    for (int j=0;j<8;++j) o[j] = 0;
  }
  *(bf16x8*)(featb + (size_t)row*KPAD + kc*8) = o;
}

__device__ __forceinline__ void scan_body(const int* __restrict__ degp,
    int* __restrict__ row_ptr, int* part){
  const int t = threadIdx.x;
  const int base = t * 80;
  int s = 0;
  for (int j=0;j<80;++j){ int i = base+j; s += (i < NNODES) ? degp[i] : 0; }
  part[t] = s;
  __syncthreads();
  for (int off=1; off<512; off<<=1){
    int x = (t >= off) ? part[t-off] : 0;
    __syncthreads();
    part[t] += x;
    __syncthreads();
  }
  int run = (t > 0) ? part[t-1] : 0;
  for (int j=0;j<80;++j){
    int i = base+j;
    if (i <= NNODES){
      row_ptr[i] = run;
      if (i < NNODES) run += degp[i];
    }
  }
}

// ---------------- alpha body: per-node segment softmax (16-lane groups) ----------------
__device__ __forceinline__ void alpha_body(int b, int voff,
    const int* __restrict__ row_ptr, const int* __restrict__ csr_src,
    const float* __restrict__ a_src, const float* __restrict__ a_dst,
    float* __restrict__ csr_alpha){
  int gid = b*256 + threadIdx.x;
  int v = voff + (gid >> 4), lane = gid & 15;
  if (v >= NNODES) return;
  int p0 = row_ptr[v], p1 = row_ptr[v+1];
  if (p0 >= p1) return;
  float ad = a_dst[v];
  float m = -1e30f;
  for (int p = p0 + lane; p < p1; p += 16){
    float s = 1.f/(1.f + __expf(-(a_src[csr_src[p]] + ad)));
    m = fmaxf(m, s);
  }
  #pragma unroll
  for (int off=8; off>0; off>>=1) m = fmaxf(m, __shfl_xor(m, off));
  float sum = 0.f;
  for (int p = p0 + lane; p < p1; p += 16){
    float s = 1.f/(1.f + __expf(-(a_src[csr_src[p]] + ad)));
    float e = __expf(s - m);
    csr_alpha[p] = e;
    sum += e;
  }
  #pragma unroll
  for (int off=8; off>0; off>>=1) sum += __shfl_xor(sum, off);
  float inv = 1.f/(sum + 1e-16f);
  for (int p = p0 + lane; p < p1; p += 16) csr_alpha[p] *= inv;
}

// ---------------- agg1 body: pure scalar-indexed gather ----------------
__device__ __forceinline__ void agg1_body(int b, int voff, const ushort* __restrict__ X,
    const int* __restrict__ row_ptr, const int* __restrict__ csr_src,
    const float* __restrict__ csr_alpha, ushort* __restrict__ outb){
  int gid = b*256 + threadIdx.x;
  int v = voff + (gid >> 6), lane = gid & 63;
  if (v >= NNODES) return;
  int p0 = __builtin_amdgcn_readfirstlane(row_ptr[v]);
  int p1 = __builtin_amdgcn_readfirstlane(row_ptr[v+1]);
  float acc[8] = {0.f,0.f,0.f,0.f,0.f,0.f,0.f,0.f};
  int p = p0;
  for (; p + 8 <= p1; p += 8){
    int s[8]; float A[8];
    #pragma unroll
    for (int u=0;u<8;++u){ s[u] = csr_src[p+u]; A[u] = csr_alpha[p+u]; }
    bf16x8 x[8];
    #pragma unroll
    for (int u=0;u<8;++u) x[u] = *(const bf16x8*)(X + (size_t)s[u]*HIDD + lane*8);
    #pragma unroll
    for (int u=0;u<8;++u)
      #pragma unroll
      for (int k=0;k<8;++k) acc[k] += A[u] * bf2f((ushort)x[u][k]);
  }
  for (; p + 4 <= p1; p += 4){
    int s0 = csr_src[p], s1 = csr_src[p+1], s2 = csr_src[p+2], s3 = csr_src[p+3];
    float A0 = csr_alpha[p], A1 = csr_alpha[p+1], A2 = csr_alpha[p+2], A3 = csr_alpha[p+3];
    bf16x8 x0 = *(const bf16x8*)(X + (size_t)s0*HIDD + lane*8);
    bf16x8 x1 = *(const bf16x8*)(X + (size_t)s1*HIDD + lane*8);
    bf16x8 x2 = *(const bf16x8*)(X + (size_t)s2*HIDD + lane*8);
    bf16x8 x3 = *(const bf16x8*)(X + (size_t)s3*HIDD + lane*8);
    #pragma unroll
    for (int k=0;k<8;++k)
      acc[k] += A0*bf2f((ushort)x0[k]) + A1*bf2f((ushort)x1[k])
              + A2*bf2f((ushort)x2[k]) + A3*bf2f((ushort)x3[k]);
  }
  for (; p < p1; ++p){
    int sj = csr_src[p];
    float aj = csr_alpha[p];
    bf16x8 xv = *(const bf16x8*)(X + (size_t)sj*HIDD + lane*8);
    #pragma unroll
    for (int k=0;k<8;++k) acc[k] += aj * bf2f((ushort)xv[k]);
  }
  bf16x8 o;
  #pragma unroll
  for (int k=0;k<8;++k){
    float a = acc[k];
    a = a > 0.f ? a : __expf(a)-1.f;
    o[k] = (short)f2bf(a);
  }
  *(bf16x8*)(outb + (size_t)v*HIDD + lane*8) = o;
}

// ---------------- K1: cast part1 | W1 | W2 | hist | W1t pad | cursor zero (512 thr) -------
#define S1_CAST   10112
#define S1_W1     (S1_CAST + 2000)
#define S1_W2     (S1_W1 + 32)
#define S1_HIST   (S1_W2 + 782)
#define S1_PAD    (S1_HIST + 48)
#define S1_CUR    (S1_PAD + 79)

__global__ __launch_bounds__(512) void setup_kernel(
    const float* __restrict__ features, const float* __restrict__ W1, const float* __restrict__ W2,
    const int* __restrict__ edst,
    ushort* __restrict__ featb, ushort* __restrict__ W1b, ushort* __restrict__ W1t,
    ushort* __restrict__ W2p, ushort* __restrict__ W2tc,
    int* __restrict__ deg, int* __restrict__ cursor){
  int b = blockIdx.x, t = threadIdx.x;
  if (b < S1_CAST){
    cast_rows2(features, featb, 0, b);
  } else if (b < S1_W1){
    int idx = (b - S1_CAST)*512 + t;           // 1,024,000 exactly
    int r = idx >> 9, c = idx & 511;
    ushort bb = f2bf(W1[idx]);
    W1b[idx] = bb;
    W1t[(size_t)c*KPAD + r] = bb;
  } else if (b < S1_W2){
    int idx = (b - S1_W1)*512 + t;             // 16384 exactly
    int k = idx >> 5, c = idx & 31;
    float val = (c < ODIM) ? W2[k*ODIM + c] : 0.f;
    ushort bb = f2bf(val);
    W2p[k*32 + c] = bb;
    W2tc[c*HIDD + k] = bb;
  } else if (b < S1_HIST){
    int e = (b - S1_W2)*512 + t;
    if (e < NEDGES) atomicAdd(&deg[edst[e]], 1);
  } else if (b < S1_PAD){
    int z = (b - S1_HIST)*512 + t;             // 24576 exactly = 512*48
    int c = z / 48, r = 2000 + (z - c*48);
    W1t[(size_t)c*KPAD + r] = 0;
  } else {
    int z = (b - S1_PAD)*512 + t;
    if (z < NNODES) cursor[z] = 0;
  }
}

// ---------------- K2: GEMM1 part1 | scan | cast part2 ----------------
#define K2_G 158
__global__ __launch_bounds__(512, 2) void gemm1a_kernel(
    const ushort* __restrict__ featb, const ushort* __restrict__ W1t, ushort* __restrict__ x1,
    const float* __restrict__ features, ushort* __restrict__ featb_w,
    const int* __restrict__ deg, int* __restrict__ row_ptr){
  __shared__ __align__(16) char smem[131072];
  int b = blockIdx.x;
  if (b < K2_G){
    int s = xcd_swz(b, K2_G);
    int row0 = (s >> 1) << 8;
    int col0 = (s & 1) << 8;
    gemm_body<ushort>(featb, W1t, x1, NNODES, HIDD, KPAD, HIDD, row0, col0, smem);
  } else if (b == K2_G){
    scan_body(deg, row_ptr, (int*)smem);
  } else {
    cast_rows2(features, featb_w, ROWSPLIT, b - K2_G - 1);
  }
}

// ---------------- K3: GEMM1 part2 | place | a_kernel part1 ----------------
#define K3_G 156
#define K3_PL (K3_G + 782)
__global__ __launch_bounds__(512, 2) void gemm1b_kernel(
    const ushort* __restrict__ featb, const ushort* __restrict__ W1t, ushort* __restrict__ x1,
    const int* __restrict__ esrc, const int* __restrict__ edst,
    const int* __restrict__ row_ptr, int* __restrict__ cursor, int* __restrict__ csr_src,
    const float* __restrict__ att_src, const float* __restrict__ att_dst,
    float* __restrict__ a_src, float* __restrict__ a_dst){
  __shared__ __align__(16) char smem[131072];
  int b = blockIdx.x, t = threadIdx.x;
  if (b < K3_G){
    int s = xcd_swz(b, K3_G);
    int row0 = ROWSPLIT + ((s >> 1) << 8);
    int col0 = (s & 1) << 8;
    gemm_body<ushort>(featb, W1t, x1, NNODES, HIDD, KPAD, HIDD, row0, col0, smem);
  } else if (b < K3_PL){
    int e = (b - K3_G)*512 + t;
    if (e < NEDGES){
      int d = edst[e];
      int pos = row_ptr[d] + atomicAdd(&cursor[d], 1);
      csr_src[pos] = esrc[e];
    }
  } else {
    int gid = (b - K3_PL)*512 + t;
    int row = gid >> 6, lane = gid & 63;     // rows [0, ROWSPLIT)
    bf16x8 v = *(const bf16x8*)(x1 + (size_t)row*HIDD + lane*8);
    float ps = 0.f, pd = 0.f;
    #pragma unroll
    for (int j=0;j<8;++j){
      float xv = bf2f((ushort)v[j]);
      ps += xv * att_src[lane*8+j];
      pd += xv * att_dst[lane*8+j];
    }
    #pragma unroll
    for (int off=32; off>0; off>>=1){ ps += __shfl_down(ps, off); pd += __shfl_down(pd, off); }
    if (lane == 0){ a_src[row] = ps; a_dst[row] = pd; }
  }
}

// ---------------- K4: a_kernel part2 ----------------
__global__ __launch_bounds__(512) void a2_kernel(const ushort* __restrict__ x1,
    const float* __restrict__ att_src, const float* __restrict__ att_dst,
    float* __restrict__ a_src, float* __restrict__ a_dst){
  int gid = blockIdx.x*512 + threadIdx.x;
  int row = ROWSPLIT + (gid >> 6), lane = gid & 63;
  if (row >= NNODES) return;
  bf16x8 v = *(const bf16x8*)(x1 + (size_t)row*HIDD + lane*8);
  float ps = 0.f, pd = 0.f;
  #pragma unroll
  for (int j=0;j<8;++j){
    float xv = bf2f((ushort)v[j]);
    ps += xv * att_src[lane*8+j];
    pd += xv * att_dst[lane*8+j];
  }
  #pragma unroll
  for (int off=32; off>0; off>>=1){ ps += __shfl_down(ps, off); pd += __shfl_down(pd, off); }
  if (lane == 0){ a_src[row] = ps; a_dst[row] = pd; }
}

// ---------------- K5: alpha nodes [0, ASPLIT) ----------------
__global__ __launch_bounds__(256) void alpha_a_kernel(const int* __restrict__ row_ptr,
    const int* __restrict__ csr_src, const float* __restrict__ a_src,
    const float* __restrict__ a_dst, float* __restrict__ csr_alpha){
  alpha_body(blockIdx.x, 0, row_ptr, csr_src, a_src, a_dst, csr_alpha);
}

// ---------------- K6: agg1 nodes [0, ASPLIT) || alpha nodes [ASPLIT, NNODES) --------------
#define OV_AGG (ASPLIT/4)
__global__ __launch_bounds__(256) void ov_kernel(const ushort* __restrict__ X,
    const int* __restrict__ row_ptr, const int* __restrict__ csr_src,
    float* __restrict__ csr_alpha, ushort* __restrict__ outb,
    const float* __restrict__ a_src, const float* __restrict__ a_dst){
  int b = blockIdx.x;
  if (b < OV_AGG){
    agg1_body(b, 0, X, row_ptr, csr_src, csr_alpha, outb);
  } else {
    alpha_body(b - OV_AGG, ASPLIT, row_ptr, csr_src, a_src, a_dst, csr_alpha);
  }
}

// ---------------- K7: agg1 nodes [ASPLIT, NNODES) ----------------
__global__ __launch_bounds__(256) void agg1b_kernel(const ushort* __restrict__ X,
    const int* __restrict__ row_ptr, const int* __restrict__ csr_src,
    const float* __restrict__ csr_alpha, ushort* __restrict__ outb){
  agg1_body(blockIdx.x, ASPLIT, X, row_ptr, csr_src, csr_alpha, outb);
}

// ---------------- h2 = h1 @ W2 (K=512, N=30) ----------------
__global__ __launch_bounds__(256) void mid_kernel(const ushort* __restrict__ h1,
    const ushort* __restrict__ W2tc, float* __restrict__ h2){
  __shared__ ushort h1s[32*512];
  __shared__ ushort w2s[32*512];
  const int t = threadIdx.x;
  const int row0 = blockIdx.x * 32;
  const ushort* g = h1 + (size_t)row0*HIDD;
  #pragma unroll
  for (int it=0; it<8; ++it){
    int ch = t + it*256;
    *(bf16x8*)&h1s[ch*8] = *(const bf16x8*)&g[ch*8];
    *(bf16x8*)&w2s[ch*8] = *(const bf16x8*)&W2tc[ch*8];
  }
  __syncthreads();
  int c = t & 31, rg = t >> 5;
  if (c < ODIM){
    float acc[4] = {0.f,0.f,0.f,0.f};
    for (int k0=0;k0<64;++k0){
      bf16x8 wv = *(const bf16x8*)&w2s[c*512 + k0*8];
      #pragma unroll
      for (int rr=0; rr<4; ++rr){
        bf16x8 hv = *(const bf16x8*)&h1s[(rg*4+rr)*HIDD + k0*8];
        #pragma unroll
        for (int j=0;j<8;++j) acc[rr] += bf2f((ushort)hv[j]) * bf2f((ushort)wv[j]);
      }
    }
    #pragma unroll
    for (int rr=0;rr<4;++rr) h2[(size_t)(row0 + rg*4 + rr)*ODIM + c] = acc[rr];
  }
}

// ---------------- conv3 fused: g[v]=sum alpha*h2[src]; h3=elu(g @ W2^T) -----
__global__ __launch_bounds__(256) void conv3_kernel(const float* __restrict__ h2,
    const int* __restrict__ row_ptr, const int* __restrict__ csr_src,
    const float* __restrict__ csr_alpha, const ushort* __restrict__ W2p,
    ushort* __restrict__ h3){
  int gid = blockIdx.x*256 + threadIdx.x;
  int v = gid >> 6, lane = gid & 63;
  if (v >= NNODES) return;
  int p0 = __builtin_amdgcn_readfirstlane(row_ptr[v]);
  int p1 = __builtin_amdgcn_readfirstlane(row_ptr[v+1]);
  float accd = 0.f;
  if (lane < ODIM){
    int p = p0;
    for (; p + 4 <= p1; p += 4){
      int s0 = csr_src[p], s1 = csr_src[p+1], s2 = csr_src[p+2], s3 = csr_src[p+3];
      float a0 = csr_alpha[p], a1 = csr_alpha[p+1], a2 = csr_alpha[p+2], a3 = csr_alpha[p+3];
      accd += a0*h2[(size_t)s0*ODIM + lane] + a1*h2[(size_t)s1*ODIM + lane]
            + a2*h2[(size_t)s2*ODIM + lane] + a3*h2[(size_t)s3*ODIM + lane];
    }
    for (; p < p1; ++p)
      accd += csr_alpha[p] * h2[(size_t)csr_src[p]*ODIM + lane];
  }
  float gv[ODIM];
  #pragma unroll
  for (int ci=0; ci<ODIM; ++ci) gv[ci] = __shfl(accd, ci);
  #pragma unroll
  for (int it=0; it<8; ++it){
    int n = it*64 + lane;
    const ushort* wrp = W2p + n*32;
    bf16x8 wvv[4];
    #pragma unroll
    for (int qd=0;qd<4;++qd) wvv[qd] = *(const bf16x8*)(wrp + qd*8);
    float acc = 0.f;
    #pragma unroll
    for (int ci=0; ci<ODIM; ++ci) acc += gv[ci]*bf2f((ushort)wvv[ci>>3][ci&7]);
    acc = acc > 0.f ? acc : __expf(acc)-1.f;
    h3[(size_t)v*HIDD + n] = f2bf(acc);
  }
}

// ---------------- GEMM4 ----------------
template<typename OutT>
__global__ __launch_bounds__(512, 2) void gemm8_kernel(
    const ushort* __restrict__ A, const ushort* __restrict__ Bt,
    OutT* __restrict__ C, int M, int N, int K, int ldc, int nwg, int cshift)
{
  __shared__ __align__(16) char smem[131072];
  int s = xcd_swz(blockIdx.x, nwg);
  int row0 = (s >> cshift) << 8;
  int col0 = (s & ((1 << cshift) - 1)) << 8;
  gemm_body<OutT>(A, Bt, C, M, N, K, ldc, row0, col0, smem);
}

extern "C" void kernel_launch(void* const* d_in, const int* in_sizes, int n_in,
                              void* d_out, int out_size, void* d_ws, size_t ws_size,
                              hipStream_t stream){
  const float* features = (const float*)d_in[0];
  const float* W1 = (const float*)d_in[1];
  const float* W2 = (const float*)d_in[2];
  const float* att_src = (const float*)d_in[3];
  const float* att_dst = (const float*)d_in[4];
  const int* edge = (const int*)d_in[5];
  const int* esrc = edge;
  const int* edst = edge + NEDGES;

  float* h2 = (float*)d_out;                              // [40000][30]
  float* h4 = h2 + (size_t)NNODES*ODIM;                   // [40000][2000]
  char* obase = (char*)h4;                                // scratch until GEMM4
  ushort* featb = (ushort*)obase;                         // [40000][2048] bf16
  ushort* x1b   = (ushort*)(obase + 163840000);           // [40000][512]
  ushort* h1b   = (ushort*)(obase + 204800000);

  char* wbase = (char*)d_ws;
  size_t o = 0;
  auto walloc = [&](size_t bytes)->void*{ void* p = wbase + o; o += (bytes + 255) & ~(size_t)255; return p; };
  ushort* h3b      = (ushort*)walloc((size_t)NNODES*HIDD*2);
  ushort* W1b      = (ushort*)walloc((size_t)INDIM*HIDD*2);
  ushort* W1t      = (ushort*)walloc((size_t)HIDD*KPAD*2);
  ushort* W2p      = (ushort*)walloc(512*32*2);
  ushort* W2tc     = (ushort*)walloc(32*512*2);
  float*  a_src    = (float*)walloc(NNODES*4);
  float*  a_dst    = (float*)walloc(NNODES*4);
  int*    deg      = (int*)walloc(NNODES*4);
  int*    cursor   = (int*)walloc(NNODES*4);
  int*    row_ptr  = (int*)walloc((NNODES+1)*4);
  int*    csr_src  = (int*)walloc(NEDGES*4);
  float*  csr_alpha= (float*)walloc(NEDGES*4);

  hipMemsetAsync(deg, 0, NNODES*4, stream);

  setup_kernel<<<S1_CUR, 512, 0, stream>>>(features, W1, W2, edst,
      featb, W1b, W1t, W2p, W2tc, deg, cursor);

  // K2: GEMM1 rows [0, 20224) || scan || cast rows [20224, 40000)
  gemm1a_kernel<<<K2_G + 1 + 9888, 512, 0, stream>>>(featb, W1t, x1b,
      features, featb, deg, row_ptr);

  // K3: GEMM1 rows [20224, 40000) || place || a rows [0, 20224)
  gemm1b_kernel<<<K3_PL + 2528, 512, 0, stream>>>(featb, W1t, x1b,
      esrc, edst, row_ptr, cursor, csr_src, att_src, att_dst, a_src, a_dst);

  a2_kernel<<<2472, 512, 0, stream>>>(x1b, att_src, att_dst, a_src, a_dst);

  // alpha [0, ASPLIT)
  alpha_a_kernel<<<ASPLIT*16/256, 256, 0, stream>>>(row_ptr, csr_src, a_src, a_dst, csr_alpha);

  // agg1 [0, ASPLIT) || alpha [ASPLIT, NNODES)
  ov_kernel<<<OV_AGG + (NNODES-ASPLIT)*16/256, 256, 0, stream>>>(x1b, row_ptr, csr_src,
      csr_alpha, h1b, a_src, a_dst);

  // agg1 [ASPLIT, NNODES)
  agg1b_kernel<<<(NNODES-ASPLIT)/4, 256, 0, stream>>>(x1b, row_ptr, csr_src, csr_alpha, h1b);

  mid_kernel<<<NNODES/32, 256, 0, stream>>>(h1b, W2tc, h2);
  conv3_kernel<<<10000, 256, 0, stream>>>(h2, row_ptr, csr_src, csr_alpha, W2p, h3b);
  gemm8_kernel<float><<<1256, 512, 0, stream>>>(h3b, W1b, h4,
      NNODES, INDIM, HIDD, INDIM, 1256, 3);
}